// Round 10
// baseline (270633.643 us; speedup 1.0000x reference)
//
#include <hip/hip_runtime.h>
#include <math.h>

#define T_TOTAL 262144
#define HID 32
#define LOG2E 1.4426950408889634f
#define TANH2C 2.8853900817779268f      /* 2*log2e */
#define NEG10LOG2E (-14.426950408889634f)
#define POS10LOG2E (14.426950408889634f)

#define PIN(x) asm volatile("" : "+v"(x))

typedef _Float16 f16x8 __attribute__((ext_vector_type(8)));
typedef float f32x4 __attribute__((ext_vector_type(4)));

__device__ __forceinline__ float fexp2(float x) { return __builtin_amdgcn_exp2f(x); }
__device__ __forceinline__ float frcp(float x)  { return __builtin_amdgcn_rcpf(x); }
__device__ __forceinline__ float fast_sig10(float x) {     // init-time only
    return frcp(1.0f + fexp2(x * NEG10LOG2E));
}
__device__ __forceinline__ float fast_tanh_clamp(float x) { // out_kernel only
    float xc = __builtin_amdgcn_fmed3f(x, -9.0f, 9.0f);
    float u  = fexp2(xc * TANH2C);
    return fmaf(-2.0f, frcp(u + 1.0f), 1.0f);
}
__device__ __forceinline__ float fast_tanh_nc(float x) {
    float u = fexp2(x * TANH2C);
    return fmaf(-2.0f, frcp(u + 1.0f), 1.0f);
}

// ---- DPP helpers -----------------------------------------------------------
template <int CTRL>
__device__ __forceinline__ float dpp_add(float v) {
    int t = __builtin_amdgcn_update_dpp(0, __float_as_int(v), CTRL, 0xF, 0xF, true);
    return v + __int_as_float(t);
}
__device__ __forceinline__ float allsum16(float x) {
    x = dpp_add<0xB1>(x);   // quad_perm xor1
    x = dpp_add<0x4E>(x);   // quad_perm xor2
    x = dpp_add<0x141>(x);  // row_half_mirror
    x = dpp_add<0x140>(x);  // row_mirror
    return x;
}
__device__ __forceinline__ int dpp_xor1_i(int v) {
    return __builtin_amdgcn_update_dpp(0, v, 0xB1, 0xF, 0xF, true);
}
__device__ __forceinline__ float rl(float x, int lane) {
    return __int_as_float(__builtin_amdgcn_readlane(__float_as_int(x), lane));
}

// ---------------------------------------------------------------------------
// Sequential RK4 scan, ONE wave. R9 structure (constant-folded scales, MFMA
// layer 2, packed-exp tail) with the h1 pack reverted to RNE (R6 form):
// RTZ pkrtz gave a systematic toward-zero bias that tripled 262k-step drift
// (absmax 0.0078 -> 0.0234). cvt(RNE) + 16-bit DPP + v_perm restores it.
// ---------------------------------------------------------------------------
__global__ __launch_bounds__(64, 1) void scan_kernel(
    const float* __restrict__ inputs,   // (T,5)
    const float* __restrict__ lday,     // (T,)
    const float* __restrict__ W1, const float* __restrict__ b1,
    const float* __restrict__ W2, const float* __restrict__ b2,
    const float* __restrict__ W3, const float* __restrict__ b3,
    float* __restrict__ traj)           // (T,2)
{
    const int lane = threadIdx.x;
    const int col  = lane & 15;
    const int quad = lane >> 4;
    const int j32  = lane & 31;

    // layer-1 weights, pre-scaled by 2log2e (tanh arg fold)
    float w1c0 = W1[0 * HID + j32] * TANH2C, w1c1 = W1[1 * HID + j32] * TANH2C;
    float w1c2 = W1[2 * HID + j32] * TANH2C, w1c3 = W1[3 * HID + j32] * TANH2C;
    float b1j = b1[j32] * TANH2C;
    PIN(w1c0); PIN(w1c1); PIN(w1c2); PIN(w1c3); PIN(b1j);

    // W2*2log2e as f16 hi/lo B-fragments: B[k][n], lane k=quad*8+jj, n=col(+16)
    f16x8 Bhi0, Blo0, Bhi1, Blo1;
#pragma unroll
    for (int jj = 0; jj < 8; ++jj) {
        float w0 = W2[(quad * 8 + jj) * HID + col] * TANH2C;
        float w1v = W2[(quad * 8 + jj) * HID + col + 16] * TANH2C;
        _Float16 h0 = (_Float16)w0, h1v = (_Float16)w1v;
        Bhi0[jj] = h0;  Blo0[jj] = (_Float16)(w0 - (float)h0);
        Bhi1[jj] = h1v; Blo1[jj] = (_Float16)(w1v - (float)h1v);
    }
    PIN(Bhi0); PIN(Blo0); PIN(Bhi1); PIN(Blo1);

    // b2*2log2e folded into MFMA C-operand (splat; rows identical anyway)
    float b2a2 = b2[col] * TANH2C, b2b2 = b2[col + 16] * TANH2C;
    f32x4 cb0 = {b2a2, b2a2, b2a2, b2a2};
    f32x4 cb1 = {b2b2, b2b2, b2b2, b2b2};
    PIN(cb0); PIN(cb1);

    // layer-3 weights pre-scaled by log2e (exp arg fold)
    float wqa = W3[col * 5 + quad] * LOG2E;
    float wqb = W3[(col + 16) * 5 + quad] * LOG2E;
    float w4a = W3[col * 5 + 4] * LOG2E;
    float w4b = W3[(col + 16) * 5 + 4] * LOG2E;
    PIN(wqa); PIN(wqb); PIN(w4a); PIN(w4b);

    // packed-exp lane masks (R6 layout) + bias fold
    float mcol0 = (col == 0) ? 1.f : 0.f;      // z_quad (o0..o3 on rows 0..3)
    float m1 = (col == 1) ? 1.f : 0.f;         // o4
    float m2 = (col == 2) ? 1.f : 0.f;         // sig10(s0)
    float m3 = (col == 3) ? 1.f : 0.f;         // sig10(s1)
    float m4 = (col == 4) ? 1.f : 0.f;         // next-step stm_mid
    float m5 = (col == 5) ? 1.f : 0.f;         // next-step stm_B
    float sig1m = (col >= 2 && col <= 5) ? 1.f : 0.f;
    float zconst = mcol0 * (b3[quad] * LOG2E) + m1 * (b3[4] * LOG2E);
    PIN(mcol0); PIN(m1); PIN(m2); PIN(m3); PIN(m4); PIN(m5);
    PIN(sig1m); PIN(zconst);

    // pack selector + bpermute byte addrs (f16 pair m lives in lane 2m)
    int psel = (lane & 1) ? 0x01000504 : 0x05040100;
    int bp0 = 32 * quad, bp1 = bp0 + 8, bp2 = bp0 + 16, bp3 = bp0 + 24;
    PIN(psel); PIN(bp0); PIN(bp1); PIN(bp2); PIN(bp3);

    double y0 = (double)inputs[0];
    double y1 = (double)inputs[1];
    float2* traj2 = (float2*)traj;
    if (lane == 0) traj2[0] = make_float2((float)y0, (float)y1);

    auto rhs = [&](float s0, float s1, float base, float stm, float ld, float zoffk,
                   float& d0, float& d1, float& rout) {
        // off-chain: sigmoid args for the packed exp
        float zs0 = s0 * NEG10LOG2E;
        float zs1 = s1 * NEG10LOG2E;
        float zoff = fmaf(zs0, m2, zs1 * m3) + zoffk;
        // layer 1 (arg pre-scaled; no clamp needed: exp2(inf) -> h1=+-1)
        float pre2 = fmaf(s1, w1c1, fmaf(s0, w1c0, base));
        float u1 = fexp2(pre2);
        float h1 = fmaf(-2.0f, frcp(u1 + 1.0f), 1.0f);
        // RNE pack of neighbor f16 pair: cvt -> 16-bit DPP xor1 -> v_perm
        union { _Float16 h; unsigned short u; } cv; cv.h = (_Float16)h1;
        int own = (int)cv.u;
        int nb  = dpp_xor1_i(own);
        int pk  = __builtin_amdgcn_perm(nb, own, psel);
        int g0i = __builtin_amdgcn_ds_bpermute(bp0, pk);
        int g1i = __builtin_amdgcn_ds_bpermute(bp1, pk);
        int g2i = __builtin_amdgcn_ds_bpermute(bp2, pk);
        int g3i = __builtin_amdgcn_ds_bpermute(bp3, pk);
        union { int i[4]; f16x8 h; } au;
        au.i[0] = g0i; au.i[1] = g1i; au.i[2] = g2i; au.i[3] = g3i;
        f16x8 A = au.h;
        // layer 2: 4 independent MFMAs; b2 folded into C of the hi pair
        f32x4 zz = {0.f, 0.f, 0.f, 0.f};
        f32x4 chi0 = __builtin_amdgcn_mfma_f32_16x16x32_f16(A, Bhi0, cb0, 0, 0, 0);
        f32x4 clo0 = __builtin_amdgcn_mfma_f32_16x16x32_f16(A, Blo0, zz, 0, 0, 0);
        f32x4 chi1 = __builtin_amdgcn_mfma_f32_16x16x32_f16(A, Bhi1, cb1, 0, 0, 0);
        f32x4 clo1 = __builtin_amdgcn_mfma_f32_16x16x32_f16(A, Blo1, zz, 0, 0, 0);
        // g = tanh(preact); arg already scaled by 2log2e
        float ua = fexp2(chi0[0] + clo0[0]);
        float ub = fexp2(chi1[0] + clo1[0]);
        float g0 = fmaf(-2.0f, frcp(ua + 1.0f), 1.0f);   // unit col
        float g1 = fmaf(-2.0f, frcp(ub + 1.0f), 1.0f);   // unit col+16
        // layer 3: two butterflies (row q -> o_q*log2e; second -> o4*log2e)
        float c1 = fmaf(g0, wqa, g1 * wqb);
        float c4 = fmaf(g0, w4a, g1 * w4b);
        float s1r = allsum16(c1);
        float s4r = allsum16(c4);
        float zarg = fmaf(s1r, mcol0, fmaf(s4r, m1, zoff));
        // ONE packed exp2 + rcp for the whole tail
        float u = fexp2(zarg);
        float r = frcp(u + sig1m);
        float w = fmaf(0.5f, u, -0.5f * r);     // sinh on o-lanes (sig1m=0)
        float sh0 = rl(w, 0),  sh1 = rl(w, 16), sh2 = rl(w, 32);
        float e3  = rl(u, 48), e4  = rl(u, 1);
        float sg0 = rl(r, 2),  sg1 = rl(r, 3);
        float p_snow = fmaxf(sh0 * stm, 0.f);
        float p_rain = fmaxf(sh1, 0.f);
        float melt   = fmaxf(sg0 * sh2, 0.f);
        float etq    = sg1 * fmaf(e3, ld, e4);   // et + q
        d0 = p_snow - melt;
        d1 = (p_rain + melt) - etq;
        rout = r;   // lanes 4,5: next step's stm values
    };

    // pipelined stage inputs: A=step n, B=n+1, C=n+2 (raw prefetch)
    float pA = inputs[2],  tmA = inputs[3],  ldA = lday[0];
    float pB = inputs[7],  tmB = inputs[8],  ldB = lday[1];
    float pC = inputs[12], tmC = inputs[13], ldC = lday[2];
    float stmA = fast_sig10(-tmA);
    float stmB = fast_sig10(-tmB);
    float stmm = fast_sig10(-0.5f * (tmA + tmB));
    float baseA = fmaf(pA, w1c2, fmaf(tmA, w1c3, b1j));
    float baseB = fmaf(pB, w1c2, fmaf(tmB, w1c3, b1j));

    for (int n = 0; n < T_TOTAL - 1; ++n) {
        const float pm  = 0.5f * (pA + pB);
        const float tmm = 0.5f * (tmA + tmB);
        const float ldm = 0.5f * (ldA + ldB);
        const float basem = fmaf(pm, w1c2, fmaf(tmm, w1c3, b1j));
        // next step's step_fn(-tm) args + folded layer-3 biases (off-chain)
        const float ztm_m = (0.5f * (tmB + tmC)) * POS10LOG2E;
        const float ztm_b = tmC * POS10LOG2E;
        const float zoffk = fmaf(ztm_m, m4, fmaf(ztm_b, m5, zconst));

        const float fy0 = (float)y0, fy1 = (float)y1;
        float k10, k11, k20, k21, k30, k31, k40, k41, rd;
        rhs(fy0,                  fy1,                  baseA, stmA, ldA, zoffk, k10, k11, rd);
        rhs(fmaf(0.5f, k10, fy0), fmaf(0.5f, k11, fy1), basem, stmm, ldm, zoffk, k20, k21, rd);
        rhs(fmaf(0.5f, k20, fy0), fmaf(0.5f, k21, fy1), basem, stmm, ldm, zoffk, k30, k31, rd);
        rhs(fy0 + k30,            fy1 + k31,            baseB, stmB, ldB, zoffk, k40, k41, rd);
        const float stmm_n = rl(rd, 4);
        const float stmB_n = rl(rd, 5);

        const float s0sum = (k10 + 2.0f * k20) + (2.0f * k30 + k40);
        const float s1sum = (k11 + 2.0f * k21) + (2.0f * k31 + k41);
        y0 += (1.0 / 6.0) * (double)s0sum;
        y1 += (1.0 / 6.0) * (double)s1sum;

        if (lane == 0) traj2[n + 1] = make_float2((float)y0, (float)y1);

        // shift pipeline
        stmA = stmB; stmB = stmB_n; stmm = stmm_n;
        baseA = baseB;
        baseB = fmaf(pC, w1c2, fmaf(tmC, w1c3, b1j));
        pA = pB; tmA = tmB; ldA = ldB;
        pB = pC; tmB = tmC; ldB = ldC;
        const int np3 = (n + 3 < T_TOTAL) ? (n + 3) : (T_TOTAL - 1);
        pC = inputs[np3 * 5 + 2]; tmC = inputs[np3 * 5 + 3]; ldC = lday[np3];
    }
}

// ---------------------------------------------------------------------------
// Parallel readout: out[t] = mlp(relu(state), p, tm)[4]
// ---------------------------------------------------------------------------
__global__ __launch_bounds__(256) void out_kernel(
    const float* __restrict__ inputs,
    const float* __restrict__ traj,
    const float* __restrict__ W1, const float* __restrict__ b1,
    const float* __restrict__ W2, const float* __restrict__ b2,
    const float* __restrict__ W3, const float* __restrict__ b3,
    float* __restrict__ out)
{
    __shared__ float sW1[4 * HID];
    __shared__ float sb1[HID];
    __shared__ float sW2T[HID * HID];   // sW2T[j*HID+i] = W2[i][j]
    __shared__ float sb2[HID];
    __shared__ float sw3[HID];          // W3[:,4]
    for (int i = threadIdx.x; i < 4 * HID; i += 256) sW1[i] = W1[i];
    for (int i = threadIdx.x; i < HID; i += 256) {
        sb1[i] = b1[i]; sb2[i] = b2[i]; sw3[i] = W3[i * 5 + 4];
    }
    for (int idx = threadIdx.x; idx < HID * HID; idx += 256) {
        int jj = idx >> 5, ii = idx & 31;
        sW2T[idx] = W2[ii * HID + jj];
    }
    __syncthreads();

    int t = blockIdx.x * 256 + threadIdx.x;
    if (t >= T_TOTAL) return;

    float2 st = ((const float2*)traj)[t];
    float s0 = fmaxf(st.x, 0.0f);
    float s1 = fmaxf(st.y, 0.0f);
    float p  = inputs[t * 5 + 2];
    float tm = inputs[t * 5 + 3];

    float h1[HID];
#pragma unroll
    for (int jj = 0; jj < HID; ++jj) {
        float pre = fmaf(s0, sW1[jj], fmaf(s1, sW1[HID + jj],
                    fmaf(p, sW1[2 * HID + jj],
                    fmaf(tm, sW1[3 * HID + jj], sb1[jj]))));
        h1[jj] = fast_tanh_clamp(pre);
    }
    float o = b3[4];
#pragma unroll 4
    for (int jj = 0; jj < HID; ++jj) {
        float a0 = sb2[jj], a1 = 0.f, a2 = 0.f, a3 = 0.f;
#pragma unroll
        for (int ii = 0; ii < HID; ii += 4) {
            a0 = fmaf(h1[ii + 0], sW2T[jj * HID + ii + 0], a0);
            a1 = fmaf(h1[ii + 1], sW2T[jj * HID + ii + 1], a1);
            a2 = fmaf(h1[ii + 2], sW2T[jj * HID + ii + 2], a2);
            a3 = fmaf(h1[ii + 3], sW2T[jj * HID + ii + 3], a3);
        }
        o = fmaf(fast_tanh_nc((a0 + a1) + (a2 + a3)), sw3[jj], o);
    }
    out[t] = o;
}

extern "C" void kernel_launch(void* const* d_in, const int* in_sizes, int n_in,
                              void* d_out, int out_size, void* d_ws, size_t ws_size,
                              hipStream_t stream) {
    (void)in_sizes; (void)n_in; (void)out_size; (void)ws_size;
    const float* inputs = (const float*)d_in[0];
    const float* lday   = (const float*)d_in[1];
    const float* W1     = (const float*)d_in[2];
    const float* b1     = (const float*)d_in[3];
    const float* W2     = (const float*)d_in[4];
    const float* b2     = (const float*)d_in[5];
    const float* W3     = (const float*)d_in[6];
    const float* b3     = (const float*)d_in[7];
    float* out  = (float*)d_out;
    float* traj = (float*)d_ws;   // T*2 floats = 2 MB

    hipLaunchKernelGGL(scan_kernel, dim3(1), dim3(64), 0, stream,
                       inputs, lday, W1, b1, W2, b2, W3, b3, traj);
    hipLaunchKernelGGL(out_kernel, dim3((T_TOTAL + 255) / 256), dim3(256), 0, stream,
                       inputs, traj, W1, b1, W2, b2, W3, b3, out);
}

// Round 14
// 16492.393 us; speedup vs baseline: 16.4096x; 16.4096x over previous
//
#include <hip/hip_runtime.h>
#include <math.h>

#define T_TOTAL 262144
#define HID 32
#define WIN 256                       /* windows */
#define WLEN (T_TOTAL / WIN)          /* 1024 steps per window */
#define NSWEEP 16                     /* total sweeps; NSWEEP-1 corrections */
#define FD_EPS0 4.0                   /* FD perturbation on s0 (snow) */
#define FD_EPS1 8.0                   /* FD perturbation on s1 (water) */
#define LOG2E 1.4426950408889634f
#define TANH2C 2.8853900817779268f    /* 2*log2e */
#define NEG10LOG2E (-14.426950408889634f)
#define POS10LOG2E (14.426950408889634f)

#define PIN(x) asm volatile("" : "+v"(x))

typedef _Float16 f16x8 __attribute__((ext_vector_type(8)));
typedef float f32x4 __attribute__((ext_vector_type(4)));

__device__ __forceinline__ float fexp2(float x) { return __builtin_amdgcn_exp2f(x); }
__device__ __forceinline__ float frcp(float x)  { return __builtin_amdgcn_rcpf(x); }
__device__ __forceinline__ float fast_sig10(float x) {
    return frcp(1.0f + fexp2(x * NEG10LOG2E));
}
__device__ __forceinline__ float fast_tanh_clamp(float x) { // out_kernel only
    float xc = __builtin_amdgcn_fmed3f(x, -9.0f, 9.0f);
    float u  = fexp2(xc * TANH2C);
    return fmaf(-2.0f, frcp(u + 1.0f), 1.0f);
}
__device__ __forceinline__ float fast_tanh_nc(float x) {
    float u = fexp2(x * TANH2C);
    return fmaf(-2.0f, frcp(u + 1.0f), 1.0f);
}

// ---- DPP helpers -----------------------------------------------------------
template <int CTRL>
__device__ __forceinline__ float dpp_add(float v) {
    int t = __builtin_amdgcn_update_dpp(0, __float_as_int(v), CTRL, 0xF, 0xF, true);
    return v + __int_as_float(t);
}
__device__ __forceinline__ float allsum16(float x) {
    x = dpp_add<0xB1>(x);   // quad_perm xor1
    x = dpp_add<0x4E>(x);   // quad_perm xor2
    x = dpp_add<0x141>(x);  // row_half_mirror
    x = dpp_add<0x140>(x);  // row_mirror
    return x;
}
__device__ __forceinline__ int dpp_xor1_i(int v) {
    return __builtin_amdgcn_update_dpp(0, v, 0xB1, 0xF, 0xF, true);
}
__device__ __forceinline__ float rl(float x, int lane) {
    return __int_as_float(__builtin_amdgcn_readlane(__float_as_int(x), lane));
}

// ---------------------------------------------------------------------------
// init: all window ICs = global Y0 guess
// ---------------------------------------------------------------------------
__global__ void init_kernel(const float* __restrict__ inputs, double2* icg) {
    int w = blockIdx.x * blockDim.x + threadIdx.x;
    if (w < WIN) icg[w] = make_double2((double)inputs[0], (double)inputs[1]);
}

// ---------------------------------------------------------------------------
// Newton-Parareal sweep: 3*WIN blocks. Block (pert,wnd) integrates window wnd
// from icg[wnd] (+FD_EPS0 in s0 for pert=1, +FD_EPS1 in s1 for pert=2) with
// the R10 per-step machinery. pert=0 stores traj; all store E[pert*WIN+wnd].
// ---------------------------------------------------------------------------
__global__ __launch_bounds__(64, 1) void sweep_kernel(
    const float* __restrict__ inputs,   // (T,5)
    const float* __restrict__ lday,     // (T,)
    const float* __restrict__ W1, const float* __restrict__ b1,
    const float* __restrict__ W2, const float* __restrict__ b2,
    const float* __restrict__ W3, const float* __restrict__ b3,
    float* __restrict__ traj,           // (T,2)
    const double2* __restrict__ icg,    // window ICs (read)
    double2* __restrict__ E)            // end states (write), 3*WIN
{
    const int lane = threadIdx.x;
    const int col  = lane & 15;
    const int quad = lane >> 4;
    const int j32  = lane & 31;

    const int wnd  = blockIdx.x & (WIN - 1);
    const int pert = blockIdx.x >> 8;          // 0,1,2
    const int S    = wnd * WLEN;
    const int endStep = (S + WLEN < T_TOTAL - 1) ? (S + WLEN) : (T_TOTAL - 1);

    // layer-1 weights, pre-scaled by 2log2e
    float w1c0 = W1[0 * HID + j32] * TANH2C, w1c1 = W1[1 * HID + j32] * TANH2C;
    float w1c2 = W1[2 * HID + j32] * TANH2C, w1c3 = W1[3 * HID + j32] * TANH2C;
    float b1j = b1[j32] * TANH2C;
    PIN(w1c0); PIN(w1c1); PIN(w1c2); PIN(w1c3); PIN(b1j);

    // W2*2log2e as f16 hi/lo B-fragments
    f16x8 Bhi0, Blo0, Bhi1, Blo1;
#pragma unroll
    for (int jj = 0; jj < 8; ++jj) {
        float w0 = W2[(quad * 8 + jj) * HID + col] * TANH2C;
        float w1v = W2[(quad * 8 + jj) * HID + col + 16] * TANH2C;
        _Float16 h0 = (_Float16)w0, h1v = (_Float16)w1v;
        Bhi0[jj] = h0;  Blo0[jj] = (_Float16)(w0 - (float)h0);
        Bhi1[jj] = h1v; Blo1[jj] = (_Float16)(w1v - (float)h1v);
    }
    PIN(Bhi0); PIN(Blo0); PIN(Bhi1); PIN(Blo1);

    float b2a2 = b2[col] * TANH2C, b2b2 = b2[col + 16] * TANH2C;
    f32x4 cb0 = {b2a2, b2a2, b2a2, b2a2};
    f32x4 cb1 = {b2b2, b2b2, b2b2, b2b2};
    PIN(cb0); PIN(cb1);

    float wqa = W3[col * 5 + quad] * LOG2E;
    float wqb = W3[(col + 16) * 5 + quad] * LOG2E;
    float w4a = W3[col * 5 + 4] * LOG2E;
    float w4b = W3[(col + 16) * 5 + 4] * LOG2E;
    PIN(wqa); PIN(wqb); PIN(w4a); PIN(w4b);

    float mcol0 = (col == 0) ? 1.f : 0.f;
    float m1 = (col == 1) ? 1.f : 0.f;
    float m2 = (col == 2) ? 1.f : 0.f;
    float m3 = (col == 3) ? 1.f : 0.f;
    float m4 = (col == 4) ? 1.f : 0.f;
    float m5 = (col == 5) ? 1.f : 0.f;
    float sig1m = (col >= 2 && col <= 5) ? 1.f : 0.f;
    float zconst = mcol0 * (b3[quad] * LOG2E) + m1 * (b3[4] * LOG2E);
    PIN(mcol0); PIN(m1); PIN(m2); PIN(m3); PIN(m4); PIN(m5);
    PIN(sig1m); PIN(zconst);

    int psel = (lane & 1) ? 0x01000504 : 0x05040100;
    int bp0 = 32 * quad, bp1 = bp0 + 8, bp2 = bp0 + 16, bp3 = bp0 + 24;
    PIN(psel); PIN(bp0); PIN(bp1); PIN(bp2); PIN(bp3);

    double2 ic = icg[wnd];
    double y0 = ic.x + ((pert == 1) ? FD_EPS0 : 0.0);
    double y1 = ic.y + ((pert == 2) ? FD_EPS1 : 0.0);
    float2* traj2 = (float2*)traj;
    if (lane == 0 && wnd == 0 && pert == 0)
        traj2[0] = make_float2((float)y0, (float)y1);

    auto rhs = [&](float s0, float s1, float base, float stm, float ld, float zoffk,
                   float& d0, float& d1, float& rout) {
        float zs0 = s0 * NEG10LOG2E;
        float zs1 = s1 * NEG10LOG2E;
        float zoff = fmaf(zs0, m2, zs1 * m3) + zoffk;
        float pre2 = fmaf(s1, w1c1, fmaf(s0, w1c0, base));
        float u1 = fexp2(pre2);
        float h1 = fmaf(-2.0f, frcp(u1 + 1.0f), 1.0f);
        union { _Float16 h; unsigned short u; } cv; cv.h = (_Float16)h1;
        int own = (int)cv.u;
        int nb  = dpp_xor1_i(own);
        int pk  = __builtin_amdgcn_perm(nb, own, psel);
        int g0i = __builtin_amdgcn_ds_bpermute(bp0, pk);
        int g1i = __builtin_amdgcn_ds_bpermute(bp1, pk);
        int g2i = __builtin_amdgcn_ds_bpermute(bp2, pk);
        int g3i = __builtin_amdgcn_ds_bpermute(bp3, pk);
        union { int i[4]; f16x8 h; } au;
        au.i[0] = g0i; au.i[1] = g1i; au.i[2] = g2i; au.i[3] = g3i;
        f16x8 A = au.h;
        f32x4 zz = {0.f, 0.f, 0.f, 0.f};
        f32x4 chi0 = __builtin_amdgcn_mfma_f32_16x16x32_f16(A, Bhi0, cb0, 0, 0, 0);
        f32x4 clo0 = __builtin_amdgcn_mfma_f32_16x16x32_f16(A, Blo0, zz, 0, 0, 0);
        f32x4 chi1 = __builtin_amdgcn_mfma_f32_16x16x32_f16(A, Bhi1, cb1, 0, 0, 0);
        f32x4 clo1 = __builtin_amdgcn_mfma_f32_16x16x32_f16(A, Blo1, zz, 0, 0, 0);
        float ua = fexp2(chi0[0] + clo0[0]);
        float ub = fexp2(chi1[0] + clo1[0]);
        float g0 = fmaf(-2.0f, frcp(ua + 1.0f), 1.0f);
        float g1 = fmaf(-2.0f, frcp(ub + 1.0f), 1.0f);
        float c1 = fmaf(g0, wqa, g1 * wqb);
        float c4 = fmaf(g0, w4a, g1 * w4b);
        float s1r = allsum16(c1);
        float s4r = allsum16(c4);
        float zarg = fmaf(s1r, mcol0, fmaf(s4r, m1, zoff));
        float u = fexp2(zarg);
        float r = frcp(u + sig1m);
        float w = fmaf(0.5f, u, -0.5f * r);
        float sh0 = rl(w, 0),  sh1 = rl(w, 16), sh2 = rl(w, 32);
        float e3  = rl(u, 48), e4  = rl(u, 1);
        float sg0 = rl(r, 2),  sg1 = rl(r, 3);
        float p_snow = fmaxf(sh0 * stm, 0.f);
        float p_rain = fmaxf(sh1, 0.f);
        float melt   = fmaxf(sg0 * sh2, 0.f);
        float etq    = sg1 * fmaf(e3, ld, e4);
        d0 = p_snow - melt;
        d1 = (p_rain + melt) - etq;
        rout = r;
    };

    float pA = inputs[S * 5 + 2],       tmA = inputs[S * 5 + 3],       ldA = lday[S];
    float pB = inputs[(S + 1) * 5 + 2], tmB = inputs[(S + 1) * 5 + 3], ldB = lday[S + 1];
    float pC = inputs[(S + 2) * 5 + 2], tmC = inputs[(S + 2) * 5 + 3], ldC = lday[S + 2];
    float stmA = fast_sig10(-tmA);
    float stmB = fast_sig10(-tmB);
    float stmm = fast_sig10(-0.5f * (tmA + tmB));
    float baseA = fmaf(pA, w1c2, fmaf(tmA, w1c3, b1j));
    float baseB = fmaf(pB, w1c2, fmaf(tmB, w1c3, b1j));

    const bool storeTraj = (pert == 0);

    for (int n = S; n < endStep; ++n) {
        const float ldm = 0.5f * (ldA + ldB);
        const float pm  = 0.5f * (pA + pB);
        const float tmm = 0.5f * (tmA + tmB);
        const float basem = fmaf(pm, w1c2, fmaf(tmm, w1c3, b1j));
        const float ztm_m = (0.5f * (tmB + tmC)) * POS10LOG2E;
        const float ztm_b = tmC * POS10LOG2E;
        const float zoffk = fmaf(ztm_m, m4, fmaf(ztm_b, m5, zconst));

        const float fy0 = (float)y0, fy1 = (float)y1;
        float k10, k11, k20, k21, k30, k31, k40, k41, rd;
        rhs(fy0,                  fy1,                  baseA, stmA, ldA, zoffk, k10, k11, rd);
        rhs(fmaf(0.5f, k10, fy0), fmaf(0.5f, k11, fy1), basem, stmm, ldm, zoffk, k20, k21, rd);
        rhs(fmaf(0.5f, k20, fy0), fmaf(0.5f, k21, fy1), basem, stmm, ldm, zoffk, k30, k31, rd);
        rhs(fy0 + k30,            fy1 + k31,            baseB, stmB, ldB, zoffk, k40, k41, rd);
        const float stmm_n = rl(rd, 4);
        const float stmB_n = rl(rd, 5);

        const float s0sum = (k10 + 2.0f * k20) + (2.0f * k30 + k40);
        const float s1sum = (k11 + 2.0f * k21) + (2.0f * k31 + k41);
        y0 += (1.0 / 6.0) * (double)s0sum;
        y1 += (1.0 / 6.0) * (double)s1sum;

        if (lane == 0 && storeTraj)
            traj2[n + 1] = make_float2((float)y0, (float)y1);

        stmA = stmB; stmB = stmB_n; stmm = stmm_n;
        baseA = baseB;
        baseB = fmaf(pC, w1c2, fmaf(tmC, w1c3, b1j));
        pA = pB; tmA = tmB; ldA = ldB;
        pB = pC; tmB = tmC; ldB = ldC;
        const int np3 = (n + 3 < T_TOTAL) ? (n + 3) : (T_TOTAL - 1);
        pC = inputs[np3 * 5 + 2]; tmC = inputs[np3 * 5 + 3]; ldC = lday[np3];
    }

    if (lane == 0) E[pert * WIN + wnd] = make_double2(y0, y1);
}

// ---------------------------------------------------------------------------
// Sequential Newton-Parareal correction, noise-hardened:
//   J01 := 0 (water cannot create snow — R13's noise-injection path)
//   J entries clamped to physical boxes; trust region on deltas;
//   sanity clamps on corrected ICs. At the exactness front d=0, so the
//   1-window/sweep exact advance is untouched.
// ---------------------------------------------------------------------------
__global__ void correct_kernel(const float* __restrict__ inputs,
                               const double2* __restrict__ E,
                               double2* __restrict__ icg) {
    if (threadIdx.x != 0 || blockIdx.x != 0) return;
    double y0c = (double)inputs[0];
    double y1c = (double)inputs[1];
    for (int w = 0; w < WIN; ++w) {
        double2 g = icg[w];
        double d0 = y0c - g.x;
        double d1 = y1c - g.y;
        d0 = fmin(fmax(d0, -50.0), 50.0);      // trust region
        d1 = fmin(fmax(d1, -400.0), 400.0);
        icg[w] = make_double2(y0c, y1c);
        double2 e0 = E[w];
        double2 e1 = E[WIN + w];
        double2 e2 = E[2 * WIN + w];
        double J00 = (e1.x - e0.x) / FD_EPS0;  // snow contraction
        double J10 = (e1.y - e0.y) / FD_EPS0;  // melt mass transfer snow->water
        double J11 = (e2.y - e0.y) / FD_EPS1;  // water integrator mode
        J00 = fmin(fmax(J00, -0.1), 0.9);
        J10 = fmin(fmax(J10, -0.1), 1.2);
        J11 = fmin(fmax(J11,  0.0), 1.05);
        y0c = e0.x + J00 * d0;                 // J01 = 0
        y1c = e0.y + J10 * d0 + J11 * d1;
        y0c = fmin(fmax(y0c, -5.0), 1000.0);   // physical sanity
        y1c = fmin(fmax(y1c, -5.0), 5000.0);
    }
}

// ---------------------------------------------------------------------------
// Parallel readout: out[t] = mlp(relu(state), p, tm)[4]
// ---------------------------------------------------------------------------
__global__ __launch_bounds__(256) void out_kernel(
    const float* __restrict__ inputs,
    const float* __restrict__ traj,
    const float* __restrict__ W1, const float* __restrict__ b1,
    const float* __restrict__ W2, const float* __restrict__ b2,
    const float* __restrict__ W3, const float* __restrict__ b3,
    float* __restrict__ out)
{
    __shared__ float sW1[4 * HID];
    __shared__ float sb1[HID];
    __shared__ float sW2T[HID * HID];
    __shared__ float sb2[HID];
    __shared__ float sw3[HID];
    for (int i = threadIdx.x; i < 4 * HID; i += 256) sW1[i] = W1[i];
    for (int i = threadIdx.x; i < HID; i += 256) {
        sb1[i] = b1[i]; sb2[i] = b2[i]; sw3[i] = W3[i * 5 + 4];
    }
    for (int idx = threadIdx.x; idx < HID * HID; idx += 256) {
        int jj = idx >> 5, ii = idx & 31;
        sW2T[idx] = W2[ii * HID + jj];
    }
    __syncthreads();

    int t = blockIdx.x * 256 + threadIdx.x;
    if (t >= T_TOTAL) return;

    float2 st = ((const float2*)traj)[t];
    float s0 = fmaxf(st.x, 0.0f);
    float s1 = fmaxf(st.y, 0.0f);
    float p  = inputs[t * 5 + 2];
    float tm = inputs[t * 5 + 3];

    float h1[HID];
#pragma unroll
    for (int jj = 0; jj < HID; ++jj) {
        float pre = fmaf(s0, sW1[jj], fmaf(s1, sW1[HID + jj],
                    fmaf(p, sW1[2 * HID + jj],
                    fmaf(tm, sW1[3 * HID + jj], sb1[jj]))));
        h1[jj] = fast_tanh_clamp(pre);
    }
    float o = b3[4];
#pragma unroll 4
    for (int jj = 0; jj < HID; ++jj) {
        float a0 = sb2[jj], a1 = 0.f, a2 = 0.f, a3 = 0.f;
#pragma unroll
        for (int ii = 0; ii < HID; ii += 4) {
            a0 = fmaf(h1[ii + 0], sW2T[jj * HID + ii + 0], a0);
            a1 = fmaf(h1[ii + 1], sW2T[jj * HID + ii + 1], a1);
            a2 = fmaf(h1[ii + 2], sW2T[jj * HID + ii + 2], a2);
            a3 = fmaf(h1[ii + 3], sW2T[jj * HID + ii + 3], a3);
        }
        o = fmaf(fast_tanh_nc((a0 + a1) + (a2 + a3)), sw3[jj], o);
    }
    out[t] = o;
}

extern "C" void kernel_launch(void* const* d_in, const int* in_sizes, int n_in,
                              void* d_out, int out_size, void* d_ws, size_t ws_size,
                              hipStream_t stream) {
    (void)in_sizes; (void)n_in; (void)out_size; (void)ws_size;
    const float* inputs = (const float*)d_in[0];
    const float* lday   = (const float*)d_in[1];
    const float* W1     = (const float*)d_in[2];
    const float* b1     = (const float*)d_in[3];
    const float* W2     = (const float*)d_in[4];
    const float* b2     = (const float*)d_in[5];
    const float* W3     = (const float*)d_in[6];
    const float* b3     = (const float*)d_in[7];
    float* out  = (float*)d_out;
    float* traj = (float*)d_ws;                 // T*2 floats = 2 MB

    // small Parareal arrays live in d_out (scratch until out_kernel)
    char* scr = (char*)d_out;
    double2* E   = (double2*)scr;               // 3*WIN double2 = 12 KB
    double2* icg = (double2*)(scr + 16384);     // WIN double2 = 4 KB

    hipLaunchKernelGGL(init_kernel, dim3(1), dim3(WIN), 0, stream, inputs, icg);
    for (int k = 0; k < NSWEEP - 1; ++k) {
        hipLaunchKernelGGL(sweep_kernel, dim3(3 * WIN), dim3(64), 0, stream,
                           inputs, lday, W1, b1, W2, b2, W3, b3, traj, icg, E);
        hipLaunchKernelGGL(correct_kernel, dim3(1), dim3(64), 0, stream,
                           inputs, E, icg);
    }
    // final sweep: traj becomes self-consistent with the corrected ICs
    hipLaunchKernelGGL(sweep_kernel, dim3(3 * WIN), dim3(64), 0, stream,
                       inputs, lday, W1, b1, W2, b2, W3, b3, traj, icg, E);
    hipLaunchKernelGGL(out_kernel, dim3((T_TOTAL + 255) / 256), dim3(256), 0, stream,
                       inputs, traj, W1, b1, W2, b2, W3, b3, out);
}

// Round 15
// 8320.286 us; speedup vs baseline: 32.5270x; 1.9822x over previous
//
#include <hip/hip_runtime.h>
#include <math.h>

#define T_TOTAL 262144
#define HID 32
#define WIN 256                       /* windows */
#define WLEN (T_TOTAL / WIN)          /* 1024 steps per window */
#define NSWEEP 8                      /* total sweeps; NSWEEP-1 corrections */
#define FD_EPS0 4.0                   /* FD perturbation on s0 (snow) */
#define FD_EPS1 8.0                   /* FD perturbation on s1 (water) */
#define LOG2E 1.4426950408889634f
#define TANH2C 2.8853900817779268f    /* 2*log2e */
#define NEG10LOG2E (-14.426950408889634f)
#define POS10LOG2E (14.426950408889634f)

#define PIN(x) asm volatile("" : "+v"(x))

typedef _Float16 f16x8 __attribute__((ext_vector_type(8)));
typedef float f32x4 __attribute__((ext_vector_type(4)));

__device__ __forceinline__ float fexp2(float x) { return __builtin_amdgcn_exp2f(x); }
__device__ __forceinline__ float frcp(float x)  { return __builtin_amdgcn_rcpf(x); }
__device__ __forceinline__ float fast_sig10(float x) {
    return frcp(1.0f + fexp2(x * NEG10LOG2E));
}
__device__ __forceinline__ float fast_tanh_clamp(float x) { // out_kernel only
    float xc = __builtin_amdgcn_fmed3f(x, -9.0f, 9.0f);
    float u  = fexp2(xc * TANH2C);
    return fmaf(-2.0f, frcp(u + 1.0f), 1.0f);
}
__device__ __forceinline__ float fast_tanh_nc(float x) {
    float u = fexp2(x * TANH2C);
    return fmaf(-2.0f, frcp(u + 1.0f), 1.0f);
}

// ---- DPP helpers -----------------------------------------------------------
template <int CTRL>
__device__ __forceinline__ float dpp_add(float v) {
    int t = __builtin_amdgcn_update_dpp(0, __float_as_int(v), CTRL, 0xF, 0xF, true);
    return v + __int_as_float(t);
}
__device__ __forceinline__ float allsum16(float x) {
    x = dpp_add<0xB1>(x);   // quad_perm xor1
    x = dpp_add<0x4E>(x);   // quad_perm xor2
    x = dpp_add<0x141>(x);  // row_half_mirror
    x = dpp_add<0x140>(x);  // row_mirror
    return x;
}
__device__ __forceinline__ int dpp_xor1_i(int v) {
    return __builtin_amdgcn_update_dpp(0, v, 0xB1, 0xF, 0xF, true);
}
__device__ __forceinline__ float rl(float x, int lane) {
    return __int_as_float(__builtin_amdgcn_readlane(__float_as_int(x), lane));
}

// ---------------------------------------------------------------------------
// init: all window ICs = global Y0 guess
// ---------------------------------------------------------------------------
__global__ void init_kernel(const float* __restrict__ inputs, double2* icg) {
    int w = blockIdx.x * blockDim.x + threadIdx.x;
    if (w < WIN) icg[w] = make_double2((double)inputs[0], (double)inputs[1]);
}

// ---------------------------------------------------------------------------
// Newton-Parareal sweep: 3*WIN blocks. Block (pert,wnd) integrates window wnd
// from icg[wnd] (+FD_EPS0 in s0 for pert=1, +FD_EPS1 in s1 for pert=2) with
// the R10 per-step machinery. pert=0 stores traj; all store E[pert*WIN+wnd].
// ---------------------------------------------------------------------------
__global__ __launch_bounds__(64, 1) void sweep_kernel(
    const float* __restrict__ inputs,   // (T,5)
    const float* __restrict__ lday,     // (T,)
    const float* __restrict__ W1, const float* __restrict__ b1,
    const float* __restrict__ W2, const float* __restrict__ b2,
    const float* __restrict__ W3, const float* __restrict__ b3,
    float* __restrict__ traj,           // (T,2)
    const double2* __restrict__ icg,    // window ICs (read)
    double2* __restrict__ E)            // end states (write), 3*WIN
{
    const int lane = threadIdx.x;
    const int col  = lane & 15;
    const int quad = lane >> 4;
    const int j32  = lane & 31;

    const int wnd  = blockIdx.x & (WIN - 1);
    const int pert = blockIdx.x >> 8;          // 0,1,2
    const int S    = wnd * WLEN;
    const int endStep = (S + WLEN < T_TOTAL - 1) ? (S + WLEN) : (T_TOTAL - 1);

    // layer-1 weights, pre-scaled by 2log2e
    float w1c0 = W1[0 * HID + j32] * TANH2C, w1c1 = W1[1 * HID + j32] * TANH2C;
    float w1c2 = W1[2 * HID + j32] * TANH2C, w1c3 = W1[3 * HID + j32] * TANH2C;
    float b1j = b1[j32] * TANH2C;
    PIN(w1c0); PIN(w1c1); PIN(w1c2); PIN(w1c3); PIN(b1j);

    // W2*2log2e as f16 hi/lo B-fragments
    f16x8 Bhi0, Blo0, Bhi1, Blo1;
#pragma unroll
    for (int jj = 0; jj < 8; ++jj) {
        float w0 = W2[(quad * 8 + jj) * HID + col] * TANH2C;
        float w1v = W2[(quad * 8 + jj) * HID + col + 16] * TANH2C;
        _Float16 h0 = (_Float16)w0, h1v = (_Float16)w1v;
        Bhi0[jj] = h0;  Blo0[jj] = (_Float16)(w0 - (float)h0);
        Bhi1[jj] = h1v; Blo1[jj] = (_Float16)(w1v - (float)h1v);
    }
    PIN(Bhi0); PIN(Blo0); PIN(Bhi1); PIN(Blo1);

    float b2a2 = b2[col] * TANH2C, b2b2 = b2[col + 16] * TANH2C;
    f32x4 cb0 = {b2a2, b2a2, b2a2, b2a2};
    f32x4 cb1 = {b2b2, b2b2, b2b2, b2b2};
    PIN(cb0); PIN(cb1);

    float wqa = W3[col * 5 + quad] * LOG2E;
    float wqb = W3[(col + 16) * 5 + quad] * LOG2E;
    float w4a = W3[col * 5 + 4] * LOG2E;
    float w4b = W3[(col + 16) * 5 + 4] * LOG2E;
    PIN(wqa); PIN(wqb); PIN(w4a); PIN(w4b);

    float mcol0 = (col == 0) ? 1.f : 0.f;
    float m1 = (col == 1) ? 1.f : 0.f;
    float m2 = (col == 2) ? 1.f : 0.f;
    float m3 = (col == 3) ? 1.f : 0.f;
    float m4 = (col == 4) ? 1.f : 0.f;
    float m5 = (col == 5) ? 1.f : 0.f;
    float sig1m = (col >= 2 && col <= 5) ? 1.f : 0.f;
    float zconst = mcol0 * (b3[quad] * LOG2E) + m1 * (b3[4] * LOG2E);
    PIN(mcol0); PIN(m1); PIN(m2); PIN(m3); PIN(m4); PIN(m5);
    PIN(sig1m); PIN(zconst);

    int psel = (lane & 1) ? 0x01000504 : 0x05040100;
    int bp0 = 32 * quad, bp1 = bp0 + 8, bp2 = bp0 + 16, bp3 = bp0 + 24;
    PIN(psel); PIN(bp0); PIN(bp1); PIN(bp2); PIN(bp3);

    double2 ic = icg[wnd];
    double y0 = ic.x + ((pert == 1) ? FD_EPS0 : 0.0);
    double y1 = ic.y + ((pert == 2) ? FD_EPS1 : 0.0);
    float2* traj2 = (float2*)traj;
    if (lane == 0 && wnd == 0 && pert == 0)
        traj2[0] = make_float2((float)y0, (float)y1);

    auto rhs = [&](float s0, float s1, float base, float stm, float ld, float zoffk,
                   float& d0, float& d1, float& rout) {
        float zs0 = s0 * NEG10LOG2E;
        float zs1 = s1 * NEG10LOG2E;
        float zoff = fmaf(zs0, m2, zs1 * m3) + zoffk;
        float pre2 = fmaf(s1, w1c1, fmaf(s0, w1c0, base));
        float u1 = fexp2(pre2);
        float h1 = fmaf(-2.0f, frcp(u1 + 1.0f), 1.0f);
        union { _Float16 h; unsigned short u; } cv; cv.h = (_Float16)h1;
        int own = (int)cv.u;
        int nb  = dpp_xor1_i(own);
        int pk  = __builtin_amdgcn_perm(nb, own, psel);
        int g0i = __builtin_amdgcn_ds_bpermute(bp0, pk);
        int g1i = __builtin_amdgcn_ds_bpermute(bp1, pk);
        int g2i = __builtin_amdgcn_ds_bpermute(bp2, pk);
        int g3i = __builtin_amdgcn_ds_bpermute(bp3, pk);
        union { int i[4]; f16x8 h; } au;
        au.i[0] = g0i; au.i[1] = g1i; au.i[2] = g2i; au.i[3] = g3i;
        f16x8 A = au.h;
        f32x4 zz = {0.f, 0.f, 0.f, 0.f};
        f32x4 chi0 = __builtin_amdgcn_mfma_f32_16x16x32_f16(A, Bhi0, cb0, 0, 0, 0);
        f32x4 clo0 = __builtin_amdgcn_mfma_f32_16x16x32_f16(A, Blo0, zz, 0, 0, 0);
        f32x4 chi1 = __builtin_amdgcn_mfma_f32_16x16x32_f16(A, Bhi1, cb1, 0, 0, 0);
        f32x4 clo1 = __builtin_amdgcn_mfma_f32_16x16x32_f16(A, Blo1, zz, 0, 0, 0);
        float ua = fexp2(chi0[0] + clo0[0]);
        float ub = fexp2(chi1[0] + clo1[0]);
        float g0 = fmaf(-2.0f, frcp(ua + 1.0f), 1.0f);
        float g1 = fmaf(-2.0f, frcp(ub + 1.0f), 1.0f);
        float c1 = fmaf(g0, wqa, g1 * wqb);
        float c4 = fmaf(g0, w4a, g1 * w4b);
        float s1r = allsum16(c1);
        float s4r = allsum16(c4);
        float zarg = fmaf(s1r, mcol0, fmaf(s4r, m1, zoff));
        float u = fexp2(zarg);
        float r = frcp(u + sig1m);
        float w = fmaf(0.5f, u, -0.5f * r);
        float sh0 = rl(w, 0),  sh1 = rl(w, 16), sh2 = rl(w, 32);
        float e3  = rl(u, 48), e4  = rl(u, 1);
        float sg0 = rl(r, 2),  sg1 = rl(r, 3);
        float p_snow = fmaxf(sh0 * stm, 0.f);
        float p_rain = fmaxf(sh1, 0.f);
        float melt   = fmaxf(sg0 * sh2, 0.f);
        float etq    = sg1 * fmaf(e3, ld, e4);
        d0 = p_snow - melt;
        d1 = (p_rain + melt) - etq;
        rout = r;
    };

    float pA = inputs[S * 5 + 2],       tmA = inputs[S * 5 + 3],       ldA = lday[S];
    float pB = inputs[(S + 1) * 5 + 2], tmB = inputs[(S + 1) * 5 + 3], ldB = lday[S + 1];
    float pC = inputs[(S + 2) * 5 + 2], tmC = inputs[(S + 2) * 5 + 3], ldC = lday[S + 2];
    float stmA = fast_sig10(-tmA);
    float stmB = fast_sig10(-tmB);
    float stmm = fast_sig10(-0.5f * (tmA + tmB));
    float baseA = fmaf(pA, w1c2, fmaf(tmA, w1c3, b1j));
    float baseB = fmaf(pB, w1c2, fmaf(tmB, w1c3, b1j));

    const bool storeTraj = (pert == 0);

    for (int n = S; n < endStep; ++n) {
        const float ldm = 0.5f * (ldA + ldB);
        const float pm  = 0.5f * (pA + pB);
        const float tmm = 0.5f * (tmA + tmB);
        const float basem = fmaf(pm, w1c2, fmaf(tmm, w1c3, b1j));
        const float ztm_m = (0.5f * (tmB + tmC)) * POS10LOG2E;
        const float ztm_b = tmC * POS10LOG2E;
        const float zoffk = fmaf(ztm_m, m4, fmaf(ztm_b, m5, zconst));

        const float fy0 = (float)y0, fy1 = (float)y1;
        float k10, k11, k20, k21, k30, k31, k40, k41, rd;
        rhs(fy0,                  fy1,                  baseA, stmA, ldA, zoffk, k10, k11, rd);
        rhs(fmaf(0.5f, k10, fy0), fmaf(0.5f, k11, fy1), basem, stmm, ldm, zoffk, k20, k21, rd);
        rhs(fmaf(0.5f, k20, fy0), fmaf(0.5f, k21, fy1), basem, stmm, ldm, zoffk, k30, k31, rd);
        rhs(fy0 + k30,            fy1 + k31,            baseB, stmB, ldB, zoffk, k40, k41, rd);
        const float stmm_n = rl(rd, 4);
        const float stmB_n = rl(rd, 5);

        const float s0sum = (k10 + 2.0f * k20) + (2.0f * k30 + k40);
        const float s1sum = (k11 + 2.0f * k21) + (2.0f * k31 + k41);
        y0 += (1.0 / 6.0) * (double)s0sum;
        y1 += (1.0 / 6.0) * (double)s1sum;

        if (lane == 0 && storeTraj)
            traj2[n + 1] = make_float2((float)y0, (float)y1);

        stmA = stmB; stmB = stmB_n; stmm = stmm_n;
        baseA = baseB;
        baseB = fmaf(pC, w1c2, fmaf(tmC, w1c3, b1j));
        pA = pB; tmA = tmB; ldA = ldB;
        pB = pC; tmB = tmC; ldB = ldC;
        const int np3 = (n + 3 < T_TOTAL) ? (n + 3) : (T_TOTAL - 1);
        pC = inputs[np3 * 5 + 2]; tmC = inputs[np3 * 5 + 3]; ldC = lday[np3];
    }

    if (lane == 0) E[pert * WIN + wnd] = make_double2(y0, y1);
}

// ---------------------------------------------------------------------------
// Sequential Newton-Parareal correction, noise-hardened:
//   J01 := 0 (water cannot create snow — pure-noise FD entry)
//   J entries clamped to physical boxes; trust region on deltas;
//   sanity clamps on corrected ICs.
// ---------------------------------------------------------------------------
__global__ void correct_kernel(const float* __restrict__ inputs,
                               const double2* __restrict__ E,
                               double2* __restrict__ icg) {
    if (threadIdx.x != 0 || blockIdx.x != 0) return;
    double y0c = (double)inputs[0];
    double y1c = (double)inputs[1];
    for (int w = 0; w < WIN; ++w) {
        double2 g = icg[w];
        double d0 = y0c - g.x;
        double d1 = y1c - g.y;
        d0 = fmin(fmax(d0, -50.0), 50.0);      // trust region
        d1 = fmin(fmax(d1, -400.0), 400.0);
        icg[w] = make_double2(y0c, y1c);
        double2 e0 = E[w];
        double2 e1 = E[WIN + w];
        double2 e2 = E[2 * WIN + w];
        double J00 = (e1.x - e0.x) / FD_EPS0;  // snow contraction
        double J10 = (e1.y - e0.y) / FD_EPS0;  // melt mass transfer snow->water
        double J11 = (e2.y - e0.y) / FD_EPS1;  // water integrator mode
        J00 = fmin(fmax(J00, -0.1), 0.9);
        J10 = fmin(fmax(J10, -0.1), 1.2);
        J11 = fmin(fmax(J11,  0.0), 1.05);
        y0c = e0.x + J00 * d0;                 // J01 = 0
        y1c = e0.y + J10 * d0 + J11 * d1;
        y0c = fmin(fmax(y0c, -5.0), 1000.0);   // physical sanity
        y1c = fmin(fmax(y1c, -5.0), 5000.0);
    }
}

// ---------------------------------------------------------------------------
// Parallel readout: out[t] = mlp(relu(state), p, tm)[4]
// ---------------------------------------------------------------------------
__global__ __launch_bounds__(256) void out_kernel(
    const float* __restrict__ inputs,
    const float* __restrict__ traj,
    const float* __restrict__ W1, const float* __restrict__ b1,
    const float* __restrict__ W2, const float* __restrict__ b2,
    const float* __restrict__ W3, const float* __restrict__ b3,
    float* __restrict__ out)
{
    __shared__ float sW1[4 * HID];
    __shared__ float sb1[HID];
    __shared__ float sW2T[HID * HID];
    __shared__ float sb2[HID];
    __shared__ float sw3[HID];
    for (int i = threadIdx.x; i < 4 * HID; i += 256) sW1[i] = W1[i];
    for (int i = threadIdx.x; i < HID; i += 256) {
        sb1[i] = b1[i]; sb2[i] = b2[i]; sw3[i] = W3[i * 5 + 4];
    }
    for (int idx = threadIdx.x; idx < HID * HID; idx += 256) {
        int jj = idx >> 5, ii = idx & 31;
        sW2T[idx] = W2[ii * HID + jj];
    }
    __syncthreads();

    int t = blockIdx.x * 256 + threadIdx.x;
    if (t >= T_TOTAL) return;

    float2 st = ((const float2*)traj)[t];
    float s0 = fmaxf(st.x, 0.0f);
    float s1 = fmaxf(st.y, 0.0f);
    float p  = inputs[t * 5 + 2];
    float tm = inputs[t * 5 + 3];

    float h1[HID];
#pragma unroll
    for (int jj = 0; jj < HID; ++jj) {
        float pre = fmaf(s0, sW1[jj], fmaf(s1, sW1[HID + jj],
                    fmaf(p, sW1[2 * HID + jj],
                    fmaf(tm, sW1[3 * HID + jj], sb1[jj]))));
        h1[jj] = fast_tanh_clamp(pre);
    }
    float o = b3[4];
#pragma unroll 4
    for (int jj = 0; jj < HID; ++jj) {
        float a0 = sb2[jj], a1 = 0.f, a2 = 0.f, a3 = 0.f;
#pragma unroll
        for (int ii = 0; ii < HID; ii += 4) {
            a0 = fmaf(h1[ii + 0], sW2T[jj * HID + ii + 0], a0);
            a1 = fmaf(h1[ii + 1], sW2T[jj * HID + ii + 1], a1);
            a2 = fmaf(h1[ii + 2], sW2T[jj * HID + ii + 2], a2);
            a3 = fmaf(h1[ii + 3], sW2T[jj * HID + ii + 3], a3);
        }
        o = fmaf(fast_tanh_nc((a0 + a1) + (a2 + a3)), sw3[jj], o);
    }
    out[t] = o;
}

extern "C" void kernel_launch(void* const* d_in, const int* in_sizes, int n_in,
                              void* d_out, int out_size, void* d_ws, size_t ws_size,
                              hipStream_t stream) {
    (void)in_sizes; (void)n_in; (void)out_size; (void)ws_size;
    const float* inputs = (const float*)d_in[0];
    const float* lday   = (const float*)d_in[1];
    const float* W1     = (const float*)d_in[2];
    const float* b1     = (const float*)d_in[3];
    const float* W2     = (const float*)d_in[4];
    const float* b2     = (const float*)d_in[5];
    const float* W3     = (const float*)d_in[6];
    const float* b3     = (const float*)d_in[7];
    float* out  = (float*)d_out;
    float* traj = (float*)d_ws;                 // T*2 floats = 2 MB

    // small Parareal arrays live in d_out (scratch until out_kernel)
    char* scr = (char*)d_out;
    double2* E   = (double2*)scr;               // 3*WIN double2 = 12 KB
    double2* icg = (double2*)(scr + 16384);     // WIN double2 = 4 KB

    hipLaunchKernelGGL(init_kernel, dim3(1), dim3(WIN), 0, stream, inputs, icg);
    for (int k = 0; k < NSWEEP - 1; ++k) {
        hipLaunchKernelGGL(sweep_kernel, dim3(3 * WIN), dim3(64), 0, stream,
                           inputs, lday, W1, b1, W2, b2, W3, b3, traj, icg, E);
        hipLaunchKernelGGL(correct_kernel, dim3(1), dim3(64), 0, stream,
                           inputs, E, icg);
    }
    // final sweep: traj becomes self-consistent with the corrected ICs
    hipLaunchKernelGGL(sweep_kernel, dim3(3 * WIN), dim3(64), 0, stream,
                       inputs, lday, W1, b1, W2, b2, W3, b3, traj, icg, E);
    hipLaunchKernelGGL(out_kernel, dim3((T_TOTAL + 255) / 256), dim3(256), 0, stream,
                       inputs, traj, W1, b1, W2, b2, W3, b3, out);
}

// Round 16
// 6246.796 us; speedup vs baseline: 43.3236x; 1.3319x over previous
//
#include <hip/hip_runtime.h>
#include <math.h>

#define T_TOTAL 262144
#define HID 32
#define WIN 256                       /* windows */
#define WLEN (T_TOTAL / WIN)          /* 1024 steps per window */
#define NSWEEP 6                      /* total sweeps; NSWEEP-1 corrections */
#define FD_EPS0 4.0                   /* FD perturbation on s0 (snow) */
#define FD_EPS1 8.0                   /* FD perturbation on s1 (water) */
#define LOG2E 1.4426950408889634f
#define TANH2C 2.8853900817779268f    /* 2*log2e */
#define NEG10LOG2E (-14.426950408889634f)
#define POS10LOG2E (14.426950408889634f)

#define PIN(x) asm volatile("" : "+v"(x))

typedef _Float16 f16x8 __attribute__((ext_vector_type(8)));
typedef float f32x4 __attribute__((ext_vector_type(4)));

__device__ __forceinline__ float fexp2(float x) { return __builtin_amdgcn_exp2f(x); }
__device__ __forceinline__ float frcp(float x)  { return __builtin_amdgcn_rcpf(x); }
__device__ __forceinline__ float fast_sig10(float x) {
    return frcp(1.0f + fexp2(x * NEG10LOG2E));
}
__device__ __forceinline__ float fast_tanh_clamp(float x) { // out_kernel only
    float xc = __builtin_amdgcn_fmed3f(x, -9.0f, 9.0f);
    float u  = fexp2(xc * TANH2C);
    return fmaf(-2.0f, frcp(u + 1.0f), 1.0f);
}
__device__ __forceinline__ float fast_tanh_nc(float x) {
    float u = fexp2(x * TANH2C);
    return fmaf(-2.0f, frcp(u + 1.0f), 1.0f);
}

// ---- DPP helpers -----------------------------------------------------------
template <int CTRL>
__device__ __forceinline__ float dpp_add(float v) {
    int t = __builtin_amdgcn_update_dpp(0, __float_as_int(v), CTRL, 0xF, 0xF, true);
    return v + __int_as_float(t);
}
__device__ __forceinline__ float allsum16(float x) {
    x = dpp_add<0xB1>(x);   // quad_perm xor1
    x = dpp_add<0x4E>(x);   // quad_perm xor2
    x = dpp_add<0x141>(x);  // row_half_mirror
    x = dpp_add<0x140>(x);  // row_mirror
    return x;
}
__device__ __forceinline__ int dpp_xor1_i(int v) {
    return __builtin_amdgcn_update_dpp(0, v, 0xB1, 0xF, 0xF, true);
}
__device__ __forceinline__ float rl(float x, int lane) {
    return __int_as_float(__builtin_amdgcn_readlane(__float_as_int(x), lane));
}

// ---------------------------------------------------------------------------
// init: all window ICs = global Y0 guess
// ---------------------------------------------------------------------------
__global__ void init_kernel(const float* __restrict__ inputs, double2* icg) {
    int w = blockIdx.x * blockDim.x + threadIdx.x;
    if (w < WIN) icg[w] = make_double2((double)inputs[0], (double)inputs[1]);
}

// ---------------------------------------------------------------------------
// Newton-Parareal sweep: 3*WIN blocks. Block (pert,wnd) integrates window wnd
// from icg[wnd] (+FD_EPS0 in s0 for pert=1, +FD_EPS1 in s1 for pert=2) with
// the R10 per-step machinery. pert=0 stores traj; all store E[pert*WIN+wnd].
// ---------------------------------------------------------------------------
__global__ __launch_bounds__(64, 1) void sweep_kernel(
    const float* __restrict__ inputs,   // (T,5)
    const float* __restrict__ lday,     // (T,)
    const float* __restrict__ W1, const float* __restrict__ b1,
    const float* __restrict__ W2, const float* __restrict__ b2,
    const float* __restrict__ W3, const float* __restrict__ b3,
    float* __restrict__ traj,           // (T,2)
    const double2* __restrict__ icg,    // window ICs (read)
    double2* __restrict__ E)            // end states (write), 3*WIN
{
    const int lane = threadIdx.x;
    const int col  = lane & 15;
    const int quad = lane >> 4;
    const int j32  = lane & 31;

    const int wnd  = blockIdx.x & (WIN - 1);
    const int pert = blockIdx.x >> 8;          // 0,1,2
    const int S    = wnd * WLEN;
    const int endStep = (S + WLEN < T_TOTAL - 1) ? (S + WLEN) : (T_TOTAL - 1);

    // layer-1 weights, pre-scaled by 2log2e
    float w1c0 = W1[0 * HID + j32] * TANH2C, w1c1 = W1[1 * HID + j32] * TANH2C;
    float w1c2 = W1[2 * HID + j32] * TANH2C, w1c3 = W1[3 * HID + j32] * TANH2C;
    float b1j = b1[j32] * TANH2C;
    PIN(w1c0); PIN(w1c1); PIN(w1c2); PIN(w1c3); PIN(b1j);

    // W2*2log2e as f16 hi/lo B-fragments
    f16x8 Bhi0, Blo0, Bhi1, Blo1;
#pragma unroll
    for (int jj = 0; jj < 8; ++jj) {
        float w0 = W2[(quad * 8 + jj) * HID + col] * TANH2C;
        float w1v = W2[(quad * 8 + jj) * HID + col + 16] * TANH2C;
        _Float16 h0 = (_Float16)w0, h1v = (_Float16)w1v;
        Bhi0[jj] = h0;  Blo0[jj] = (_Float16)(w0 - (float)h0);
        Bhi1[jj] = h1v; Blo1[jj] = (_Float16)(w1v - (float)h1v);
    }
    PIN(Bhi0); PIN(Blo0); PIN(Bhi1); PIN(Blo1);

    float b2a2 = b2[col] * TANH2C, b2b2 = b2[col + 16] * TANH2C;
    f32x4 cb0 = {b2a2, b2a2, b2a2, b2a2};
    f32x4 cb1 = {b2b2, b2b2, b2b2, b2b2};
    PIN(cb0); PIN(cb1);

    float wqa = W3[col * 5 + quad] * LOG2E;
    float wqb = W3[(col + 16) * 5 + quad] * LOG2E;
    float w4a = W3[col * 5 + 4] * LOG2E;
    float w4b = W3[(col + 16) * 5 + 4] * LOG2E;
    PIN(wqa); PIN(wqb); PIN(w4a); PIN(w4b);

    float mcol0 = (col == 0) ? 1.f : 0.f;
    float m1 = (col == 1) ? 1.f : 0.f;
    float m2 = (col == 2) ? 1.f : 0.f;
    float m3 = (col == 3) ? 1.f : 0.f;
    float m4 = (col == 4) ? 1.f : 0.f;
    float m5 = (col == 5) ? 1.f : 0.f;
    float sig1m = (col >= 2 && col <= 5) ? 1.f : 0.f;
    float zconst = mcol0 * (b3[quad] * LOG2E) + m1 * (b3[4] * LOG2E);
    PIN(mcol0); PIN(m1); PIN(m2); PIN(m3); PIN(m4); PIN(m5);
    PIN(sig1m); PIN(zconst);

    int psel = (lane & 1) ? 0x01000504 : 0x05040100;
    int bp0 = 32 * quad, bp1 = bp0 + 8, bp2 = bp0 + 16, bp3 = bp0 + 24;
    PIN(psel); PIN(bp0); PIN(bp1); PIN(bp2); PIN(bp3);

    double2 ic = icg[wnd];
    double y0 = ic.x + ((pert == 1) ? FD_EPS0 : 0.0);
    double y1 = ic.y + ((pert == 2) ? FD_EPS1 : 0.0);
    float2* traj2 = (float2*)traj;
    if (lane == 0 && wnd == 0 && pert == 0)
        traj2[0] = make_float2((float)y0, (float)y1);

    auto rhs = [&](float s0, float s1, float base, float stm, float ld, float zoffk,
                   float& d0, float& d1, float& rout) {
        float zs0 = s0 * NEG10LOG2E;
        float zs1 = s1 * NEG10LOG2E;
        float zoff = fmaf(zs0, m2, zs1 * m3) + zoffk;
        float pre2 = fmaf(s1, w1c1, fmaf(s0, w1c0, base));
        float u1 = fexp2(pre2);
        float h1 = fmaf(-2.0f, frcp(u1 + 1.0f), 1.0f);
        union { _Float16 h; unsigned short u; } cv; cv.h = (_Float16)h1;
        int own = (int)cv.u;
        int nb  = dpp_xor1_i(own);
        int pk  = __builtin_amdgcn_perm(nb, own, psel);
        int g0i = __builtin_amdgcn_ds_bpermute(bp0, pk);
        int g1i = __builtin_amdgcn_ds_bpermute(bp1, pk);
        int g2i = __builtin_amdgcn_ds_bpermute(bp2, pk);
        int g3i = __builtin_amdgcn_ds_bpermute(bp3, pk);
        union { int i[4]; f16x8 h; } au;
        au.i[0] = g0i; au.i[1] = g1i; au.i[2] = g2i; au.i[3] = g3i;
        f16x8 A = au.h;
        f32x4 zz = {0.f, 0.f, 0.f, 0.f};
        f32x4 chi0 = __builtin_amdgcn_mfma_f32_16x16x32_f16(A, Bhi0, cb0, 0, 0, 0);
        f32x4 clo0 = __builtin_amdgcn_mfma_f32_16x16x32_f16(A, Blo0, zz, 0, 0, 0);
        f32x4 chi1 = __builtin_amdgcn_mfma_f32_16x16x32_f16(A, Bhi1, cb1, 0, 0, 0);
        f32x4 clo1 = __builtin_amdgcn_mfma_f32_16x16x32_f16(A, Blo1, zz, 0, 0, 0);
        float ua = fexp2(chi0[0] + clo0[0]);
        float ub = fexp2(chi1[0] + clo1[0]);
        float g0 = fmaf(-2.0f, frcp(ua + 1.0f), 1.0f);
        float g1 = fmaf(-2.0f, frcp(ub + 1.0f), 1.0f);
        float c1 = fmaf(g0, wqa, g1 * wqb);
        float c4 = fmaf(g0, w4a, g1 * w4b);
        float s1r = allsum16(c1);
        float s4r = allsum16(c4);
        float zarg = fmaf(s1r, mcol0, fmaf(s4r, m1, zoff));
        float u = fexp2(zarg);
        float r = frcp(u + sig1m);
        float w = fmaf(0.5f, u, -0.5f * r);
        float sh0 = rl(w, 0),  sh1 = rl(w, 16), sh2 = rl(w, 32);
        float e3  = rl(u, 48), e4  = rl(u, 1);
        float sg0 = rl(r, 2),  sg1 = rl(r, 3);
        float p_snow = fmaxf(sh0 * stm, 0.f);
        float p_rain = fmaxf(sh1, 0.f);
        float melt   = fmaxf(sg0 * sh2, 0.f);
        float etq    = sg1 * fmaf(e3, ld, e4);
        d0 = p_snow - melt;
        d1 = (p_rain + melt) - etq;
        rout = r;
    };

    float pA = inputs[S * 5 + 2],       tmA = inputs[S * 5 + 3],       ldA = lday[S];
    float pB = inputs[(S + 1) * 5 + 2], tmB = inputs[(S + 1) * 5 + 3], ldB = lday[S + 1];
    float pC = inputs[(S + 2) * 5 + 2], tmC = inputs[(S + 2) * 5 + 3], ldC = lday[S + 2];
    float stmA = fast_sig10(-tmA);
    float stmB = fast_sig10(-tmB);
    float stmm = fast_sig10(-0.5f * (tmA + tmB));
    float baseA = fmaf(pA, w1c2, fmaf(tmA, w1c3, b1j));
    float baseB = fmaf(pB, w1c2, fmaf(tmB, w1c3, b1j));

    const bool storeTraj = (pert == 0);

    for (int n = S; n < endStep; ++n) {
        const float ldm = 0.5f * (ldA + ldB);
        const float pm  = 0.5f * (pA + pB);
        const float tmm = 0.5f * (tmA + tmB);
        const float basem = fmaf(pm, w1c2, fmaf(tmm, w1c3, b1j));
        const float ztm_m = (0.5f * (tmB + tmC)) * POS10LOG2E;
        const float ztm_b = tmC * POS10LOG2E;
        const float zoffk = fmaf(ztm_m, m4, fmaf(ztm_b, m5, zconst));

        const float fy0 = (float)y0, fy1 = (float)y1;
        float k10, k11, k20, k21, k30, k31, k40, k41, rd;
        rhs(fy0,                  fy1,                  baseA, stmA, ldA, zoffk, k10, k11, rd);
        rhs(fmaf(0.5f, k10, fy0), fmaf(0.5f, k11, fy1), basem, stmm, ldm, zoffk, k20, k21, rd);
        rhs(fmaf(0.5f, k20, fy0), fmaf(0.5f, k21, fy1), basem, stmm, ldm, zoffk, k30, k31, rd);
        rhs(fy0 + k30,            fy1 + k31,            baseB, stmB, ldB, zoffk, k40, k41, rd);
        const float stmm_n = rl(rd, 4);
        const float stmB_n = rl(rd, 5);

        const float s0sum = (k10 + 2.0f * k20) + (2.0f * k30 + k40);
        const float s1sum = (k11 + 2.0f * k21) + (2.0f * k31 + k41);
        y0 += (1.0 / 6.0) * (double)s0sum;
        y1 += (1.0 / 6.0) * (double)s1sum;

        if (lane == 0 && storeTraj)
            traj2[n + 1] = make_float2((float)y0, (float)y1);

        stmA = stmB; stmB = stmB_n; stmm = stmm_n;
        baseA = baseB;
        baseB = fmaf(pC, w1c2, fmaf(tmC, w1c3, b1j));
        pA = pB; tmA = tmB; ldA = ldB;
        pB = pC; tmB = tmC; ldB = ldC;
        const int np3 = (n + 3 < T_TOTAL) ? (n + 3) : (T_TOTAL - 1);
        pC = inputs[np3 * 5 + 2]; tmC = inputs[np3 * 5 + 3]; ldC = lday[np3];
    }

    if (lane == 0) E[pert * WIN + wnd] = make_double2(y0, y1);
}

// ---------------------------------------------------------------------------
// Sequential Newton-Parareal correction, noise-hardened:
//   J01 := 0 (water cannot create snow — pure-noise FD entry)
//   J entries clamped to physical boxes; trust region on deltas;
//   sanity clamps on corrected ICs.
// ---------------------------------------------------------------------------
__global__ void correct_kernel(const float* __restrict__ inputs,
                               const double2* __restrict__ E,
                               double2* __restrict__ icg) {
    if (threadIdx.x != 0 || blockIdx.x != 0) return;
    double y0c = (double)inputs[0];
    double y1c = (double)inputs[1];
    for (int w = 0; w < WIN; ++w) {
        double2 g = icg[w];
        double d0 = y0c - g.x;
        double d1 = y1c - g.y;
        d0 = fmin(fmax(d0, -50.0), 50.0);      // trust region
        d1 = fmin(fmax(d1, -400.0), 400.0);
        icg[w] = make_double2(y0c, y1c);
        double2 e0 = E[w];
        double2 e1 = E[WIN + w];
        double2 e2 = E[2 * WIN + w];
        double J00 = (e1.x - e0.x) / FD_EPS0;  // snow contraction
        double J10 = (e1.y - e0.y) / FD_EPS0;  // melt mass transfer snow->water
        double J11 = (e2.y - e0.y) / FD_EPS1;  // water integrator mode
        J00 = fmin(fmax(J00, -0.1), 0.9);
        J10 = fmin(fmax(J10, -0.1), 1.2);
        J11 = fmin(fmax(J11,  0.0), 1.05);
        y0c = e0.x + J00 * d0;                 // J01 = 0
        y1c = e0.y + J10 * d0 + J11 * d1;
        y0c = fmin(fmax(y0c, -5.0), 1000.0);   // physical sanity
        y1c = fmin(fmax(y1c, -5.0), 5000.0);
    }
}

// ---------------------------------------------------------------------------
// Parallel readout: out[t] = mlp(relu(state), p, tm)[4]
// ---------------------------------------------------------------------------
__global__ __launch_bounds__(256) void out_kernel(
    const float* __restrict__ inputs,
    const float* __restrict__ traj,
    const float* __restrict__ W1, const float* __restrict__ b1,
    const float* __restrict__ W2, const float* __restrict__ b2,
    const float* __restrict__ W3, const float* __restrict__ b3,
    float* __restrict__ out)
{
    __shared__ float sW1[4 * HID];
    __shared__ float sb1[HID];
    __shared__ float sW2T[HID * HID];
    __shared__ float sb2[HID];
    __shared__ float sw3[HID];
    for (int i = threadIdx.x; i < 4 * HID; i += 256) sW1[i] = W1[i];
    for (int i = threadIdx.x; i < HID; i += 256) {
        sb1[i] = b1[i]; sb2[i] = b2[i]; sw3[i] = W3[i * 5 + 4];
    }
    for (int idx = threadIdx.x; idx < HID * HID; idx += 256) {
        int jj = idx >> 5, ii = idx & 31;
        sW2T[idx] = W2[ii * HID + jj];
    }
    __syncthreads();

    int t = blockIdx.x * 256 + threadIdx.x;
    if (t >= T_TOTAL) return;

    float2 st = ((const float2*)traj)[t];
    float s0 = fmaxf(st.x, 0.0f);
    float s1 = fmaxf(st.y, 0.0f);
    float p  = inputs[t * 5 + 2];
    float tm = inputs[t * 5 + 3];

    float h1[HID];
#pragma unroll
    for (int jj = 0; jj < HID; ++jj) {
        float pre = fmaf(s0, sW1[jj], fmaf(s1, sW1[HID + jj],
                    fmaf(p, sW1[2 * HID + jj],
                    fmaf(tm, sW1[3 * HID + jj], sb1[jj]))));
        h1[jj] = fast_tanh_clamp(pre);
    }
    float o = b3[4];
#pragma unroll 4
    for (int jj = 0; jj < HID; ++jj) {
        float a0 = sb2[jj], a1 = 0.f, a2 = 0.f, a3 = 0.f;
#pragma unroll
        for (int ii = 0; ii < HID; ii += 4) {
            a0 = fmaf(h1[ii + 0], sW2T[jj * HID + ii + 0], a0);
            a1 = fmaf(h1[ii + 1], sW2T[jj * HID + ii + 1], a1);
            a2 = fmaf(h1[ii + 2], sW2T[jj * HID + ii + 2], a2);
            a3 = fmaf(h1[ii + 3], sW2T[jj * HID + ii + 3], a3);
        }
        o = fmaf(fast_tanh_nc((a0 + a1) + (a2 + a3)), sw3[jj], o);
    }
    out[t] = o;
}

extern "C" void kernel_launch(void* const* d_in, const int* in_sizes, int n_in,
                              void* d_out, int out_size, void* d_ws, size_t ws_size,
                              hipStream_t stream) {
    (void)in_sizes; (void)n_in; (void)out_size; (void)ws_size;
    const float* inputs = (const float*)d_in[0];
    const float* lday   = (const float*)d_in[1];
    const float* W1     = (const float*)d_in[2];
    const float* b1     = (const float*)d_in[3];
    const float* W2     = (const float*)d_in[4];
    const float* b2     = (const float*)d_in[5];
    const float* W3     = (const float*)d_in[6];
    const float* b3     = (const float*)d_in[7];
    float* out  = (float*)d_out;
    float* traj = (float*)d_ws;                 // T*2 floats = 2 MB

    // small Parareal arrays live in d_out (scratch until out_kernel)
    char* scr = (char*)d_out;
    double2* E   = (double2*)scr;               // 3*WIN double2 = 12 KB
    double2* icg = (double2*)(scr + 16384);     // WIN double2 = 4 KB

    hipLaunchKernelGGL(init_kernel, dim3(1), dim3(WIN), 0, stream, inputs, icg);
    for (int k = 0; k < NSWEEP - 1; ++k) {
        hipLaunchKernelGGL(sweep_kernel, dim3(3 * WIN), dim3(64), 0, stream,
                           inputs, lday, W1, b1, W2, b2, W3, b3, traj, icg, E);
        hipLaunchKernelGGL(correct_kernel, dim3(1), dim3(64), 0, stream,
                           inputs, E, icg);
    }
    // final sweep: traj becomes self-consistent with the corrected ICs
    hipLaunchKernelGGL(sweep_kernel, dim3(3 * WIN), dim3(64), 0, stream,
                       inputs, lday, W1, b1, W2, b2, W3, b3, traj, icg, E);
    hipLaunchKernelGGL(out_kernel, dim3((T_TOTAL + 255) / 256), dim3(256), 0, stream,
                       inputs, traj, W1, b1, W2, b2, W3, b3, out);
}

// Round 17
// 4973.067 us; speedup vs baseline: 54.4199x; 1.2561x over previous
//
#include <hip/hip_runtime.h>
#include <math.h>

#define T_TOTAL 262144
#define HID 32
#define WIN 512                       /* windows */
#define WLEN (T_TOTAL / WIN)          /* 512 steps per window */
#define NSWEEP 6                      /* total sweeps; NSWEEP-1 corrections */
#define FD_EPS0 4.0                   /* FD perturbation on s0 (snow) */
#define FD_EPS1 8.0                   /* FD perturbation on s1 (water) */
#define LOG2E 1.4426950408889634f
#define TANH2C 2.8853900817779268f    /* 2*log2e */
#define NEG10LOG2E (-14.426950408889634f)
#define POS10LOG2E (14.426950408889634f)

#define PIN(x) asm volatile("" : "+v"(x))

typedef _Float16 f16x8 __attribute__((ext_vector_type(8)));
typedef float f32x4 __attribute__((ext_vector_type(4)));

__device__ __forceinline__ float fexp2(float x) { return __builtin_amdgcn_exp2f(x); }
__device__ __forceinline__ float frcp(float x)  { return __builtin_amdgcn_rcpf(x); }
__device__ __forceinline__ float fast_sig10(float x) {
    return frcp(1.0f + fexp2(x * NEG10LOG2E));
}
__device__ __forceinline__ float fast_tanh_clamp(float x) { // out_kernel only
    float xc = __builtin_amdgcn_fmed3f(x, -9.0f, 9.0f);
    float u  = fexp2(xc * TANH2C);
    return fmaf(-2.0f, frcp(u + 1.0f), 1.0f);
}
__device__ __forceinline__ float fast_tanh_nc(float x) {
    float u = fexp2(x * TANH2C);
    return fmaf(-2.0f, frcp(u + 1.0f), 1.0f);
}

// ---- DPP helpers -----------------------------------------------------------
template <int CTRL>
__device__ __forceinline__ float dpp_add(float v) {
    int t = __builtin_amdgcn_update_dpp(0, __float_as_int(v), CTRL, 0xF, 0xF, true);
    return v + __int_as_float(t);
}
__device__ __forceinline__ float allsum16(float x) {
    x = dpp_add<0xB1>(x);   // quad_perm xor1
    x = dpp_add<0x4E>(x);   // quad_perm xor2
    x = dpp_add<0x141>(x);  // row_half_mirror
    x = dpp_add<0x140>(x);  // row_mirror
    return x;
}
__device__ __forceinline__ int dpp_xor1_i(int v) {
    return __builtin_amdgcn_update_dpp(0, v, 0xB1, 0xF, 0xF, true);
}
__device__ __forceinline__ float rl(float x, int lane) {
    return __int_as_float(__builtin_amdgcn_readlane(__float_as_int(x), lane));
}

// ---------------------------------------------------------------------------
// init: all window ICs = global Y0 guess
// ---------------------------------------------------------------------------
__global__ void init_kernel(const float* __restrict__ inputs, double2* icg) {
    int w = blockIdx.x * blockDim.x + threadIdx.x;
    if (w < WIN) icg[w] = make_double2((double)inputs[0], (double)inputs[1]);
}

// ---------------------------------------------------------------------------
// Newton-Parareal sweep: 3*WIN blocks. Block (pert,wnd) integrates window wnd
// from icg[wnd] (+FD_EPS0 in s0 for pert=1, +FD_EPS1 in s1 for pert=2) with
// the R10 per-step machinery. pert=0 stores traj; all store E[pert*WIN+wnd].
// ---------------------------------------------------------------------------
__global__ __launch_bounds__(64, 1) void sweep_kernel(
    const float* __restrict__ inputs,   // (T,5)
    const float* __restrict__ lday,     // (T,)
    const float* __restrict__ W1, const float* __restrict__ b1,
    const float* __restrict__ W2, const float* __restrict__ b2,
    const float* __restrict__ W3, const float* __restrict__ b3,
    float* __restrict__ traj,           // (T,2)
    const double2* __restrict__ icg,    // window ICs (read)
    double2* __restrict__ E)            // end states (write), 3*WIN
{
    const int lane = threadIdx.x;
    const int col  = lane & 15;
    const int quad = lane >> 4;
    const int j32  = lane & 31;

    const int wnd  = blockIdx.x % WIN;
    const int pert = blockIdx.x / WIN;         // 0,1,2
    const int S    = wnd * WLEN;
    const int endStep = (S + WLEN < T_TOTAL - 1) ? (S + WLEN) : (T_TOTAL - 1);

    // layer-1 weights, pre-scaled by 2log2e
    float w1c0 = W1[0 * HID + j32] * TANH2C, w1c1 = W1[1 * HID + j32] * TANH2C;
    float w1c2 = W1[2 * HID + j32] * TANH2C, w1c3 = W1[3 * HID + j32] * TANH2C;
    float b1j = b1[j32] * TANH2C;
    PIN(w1c0); PIN(w1c1); PIN(w1c2); PIN(w1c3); PIN(b1j);

    // W2*2log2e as f16 hi/lo B-fragments
    f16x8 Bhi0, Blo0, Bhi1, Blo1;
#pragma unroll
    for (int jj = 0; jj < 8; ++jj) {
        float w0 = W2[(quad * 8 + jj) * HID + col] * TANH2C;
        float w1v = W2[(quad * 8 + jj) * HID + col + 16] * TANH2C;
        _Float16 h0 = (_Float16)w0, h1v = (_Float16)w1v;
        Bhi0[jj] = h0;  Blo0[jj] = (_Float16)(w0 - (float)h0);
        Bhi1[jj] = h1v; Blo1[jj] = (_Float16)(w1v - (float)h1v);
    }
    PIN(Bhi0); PIN(Blo0); PIN(Bhi1); PIN(Blo1);

    float b2a2 = b2[col] * TANH2C, b2b2 = b2[col + 16] * TANH2C;
    f32x4 cb0 = {b2a2, b2a2, b2a2, b2a2};
    f32x4 cb1 = {b2b2, b2b2, b2b2, b2b2};
    PIN(cb0); PIN(cb1);

    float wqa = W3[col * 5 + quad] * LOG2E;
    float wqb = W3[(col + 16) * 5 + quad] * LOG2E;
    float w4a = W3[col * 5 + 4] * LOG2E;
    float w4b = W3[(col + 16) * 5 + 4] * LOG2E;
    PIN(wqa); PIN(wqb); PIN(w4a); PIN(w4b);

    float mcol0 = (col == 0) ? 1.f : 0.f;
    float m1 = (col == 1) ? 1.f : 0.f;
    float m2 = (col == 2) ? 1.f : 0.f;
    float m3 = (col == 3) ? 1.f : 0.f;
    float m4 = (col == 4) ? 1.f : 0.f;
    float m5 = (col == 5) ? 1.f : 0.f;
    float sig1m = (col >= 2 && col <= 5) ? 1.f : 0.f;
    float zconst = mcol0 * (b3[quad] * LOG2E) + m1 * (b3[4] * LOG2E);
    PIN(mcol0); PIN(m1); PIN(m2); PIN(m3); PIN(m4); PIN(m5);
    PIN(sig1m); PIN(zconst);

    int psel = (lane & 1) ? 0x01000504 : 0x05040100;
    int bp0 = 32 * quad, bp1 = bp0 + 8, bp2 = bp0 + 16, bp3 = bp0 + 24;
    PIN(psel); PIN(bp0); PIN(bp1); PIN(bp2); PIN(bp3);

    double2 ic = icg[wnd];
    double y0 = ic.x + ((pert == 1) ? FD_EPS0 : 0.0);
    double y1 = ic.y + ((pert == 2) ? FD_EPS1 : 0.0);
    float2* traj2 = (float2*)traj;
    if (lane == 0 && wnd == 0 && pert == 0)
        traj2[0] = make_float2((float)y0, (float)y1);

    auto rhs = [&](float s0, float s1, float base, float stm, float ld, float zoffk,
                   float& d0, float& d1, float& rout) {
        float zs0 = s0 * NEG10LOG2E;
        float zs1 = s1 * NEG10LOG2E;
        float zoff = fmaf(zs0, m2, zs1 * m3) + zoffk;
        float pre2 = fmaf(s1, w1c1, fmaf(s0, w1c0, base));
        float u1 = fexp2(pre2);
        float h1 = fmaf(-2.0f, frcp(u1 + 1.0f), 1.0f);
        union { _Float16 h; unsigned short u; } cv; cv.h = (_Float16)h1;
        int own = (int)cv.u;
        int nb  = dpp_xor1_i(own);
        int pk  = __builtin_amdgcn_perm(nb, own, psel);
        int g0i = __builtin_amdgcn_ds_bpermute(bp0, pk);
        int g1i = __builtin_amdgcn_ds_bpermute(bp1, pk);
        int g2i = __builtin_amdgcn_ds_bpermute(bp2, pk);
        int g3i = __builtin_amdgcn_ds_bpermute(bp3, pk);
        union { int i[4]; f16x8 h; } au;
        au.i[0] = g0i; au.i[1] = g1i; au.i[2] = g2i; au.i[3] = g3i;
        f16x8 A = au.h;
        f32x4 zz = {0.f, 0.f, 0.f, 0.f};
        f32x4 chi0 = __builtin_amdgcn_mfma_f32_16x16x32_f16(A, Bhi0, cb0, 0, 0, 0);
        f32x4 clo0 = __builtin_amdgcn_mfma_f32_16x16x32_f16(A, Blo0, zz, 0, 0, 0);
        f32x4 chi1 = __builtin_amdgcn_mfma_f32_16x16x32_f16(A, Bhi1, cb1, 0, 0, 0);
        f32x4 clo1 = __builtin_amdgcn_mfma_f32_16x16x32_f16(A, Blo1, zz, 0, 0, 0);
        float ua = fexp2(chi0[0] + clo0[0]);
        float ub = fexp2(chi1[0] + clo1[0]);
        float g0 = fmaf(-2.0f, frcp(ua + 1.0f), 1.0f);
        float g1 = fmaf(-2.0f, frcp(ub + 1.0f), 1.0f);
        float c1 = fmaf(g0, wqa, g1 * wqb);
        float c4 = fmaf(g0, w4a, g1 * w4b);
        float s1r = allsum16(c1);
        float s4r = allsum16(c4);
        float zarg = fmaf(s1r, mcol0, fmaf(s4r, m1, zoff));
        float u = fexp2(zarg);
        float r = frcp(u + sig1m);
        float w = fmaf(0.5f, u, -0.5f * r);
        float sh0 = rl(w, 0),  sh1 = rl(w, 16), sh2 = rl(w, 32);
        float e3  = rl(u, 48), e4  = rl(u, 1);
        float sg0 = rl(r, 2),  sg1 = rl(r, 3);
        float p_snow = fmaxf(sh0 * stm, 0.f);
        float p_rain = fmaxf(sh1, 0.f);
        float melt   = fmaxf(sg0 * sh2, 0.f);
        float etq    = sg1 * fmaf(e3, ld, e4);
        d0 = p_snow - melt;
        d1 = (p_rain + melt) - etq;
        rout = r;
    };

    float pA = inputs[S * 5 + 2],       tmA = inputs[S * 5 + 3],       ldA = lday[S];
    float pB = inputs[(S + 1) * 5 + 2], tmB = inputs[(S + 1) * 5 + 3], ldB = lday[S + 1];
    float pC = inputs[(S + 2) * 5 + 2], tmC = inputs[(S + 2) * 5 + 3], ldC = lday[S + 2];
    float stmA = fast_sig10(-tmA);
    float stmB = fast_sig10(-tmB);
    float stmm = fast_sig10(-0.5f * (tmA + tmB));
    float baseA = fmaf(pA, w1c2, fmaf(tmA, w1c3, b1j));
    float baseB = fmaf(pB, w1c2, fmaf(tmB, w1c3, b1j));

    const bool storeTraj = (pert == 0);

    for (int n = S; n < endStep; ++n) {
        const float ldm = 0.5f * (ldA + ldB);
        const float pm  = 0.5f * (pA + pB);
        const float tmm = 0.5f * (tmA + tmB);
        const float basem = fmaf(pm, w1c2, fmaf(tmm, w1c3, b1j));
        const float ztm_m = (0.5f * (tmB + tmC)) * POS10LOG2E;
        const float ztm_b = tmC * POS10LOG2E;
        const float zoffk = fmaf(ztm_m, m4, fmaf(ztm_b, m5, zconst));

        const float fy0 = (float)y0, fy1 = (float)y1;
        float k10, k11, k20, k21, k30, k31, k40, k41, rd;
        rhs(fy0,                  fy1,                  baseA, stmA, ldA, zoffk, k10, k11, rd);
        rhs(fmaf(0.5f, k10, fy0), fmaf(0.5f, k11, fy1), basem, stmm, ldm, zoffk, k20, k21, rd);
        rhs(fmaf(0.5f, k20, fy0), fmaf(0.5f, k21, fy1), basem, stmm, ldm, zoffk, k30, k31, rd);
        rhs(fy0 + k30,            fy1 + k31,            baseB, stmB, ldB, zoffk, k40, k41, rd);
        const float stmm_n = rl(rd, 4);
        const float stmB_n = rl(rd, 5);

        const float s0sum = (k10 + 2.0f * k20) + (2.0f * k30 + k40);
        const float s1sum = (k11 + 2.0f * k21) + (2.0f * k31 + k41);
        y0 += (1.0 / 6.0) * (double)s0sum;
        y1 += (1.0 / 6.0) * (double)s1sum;

        if (lane == 0 && storeTraj)
            traj2[n + 1] = make_float2((float)y0, (float)y1);

        stmA = stmB; stmB = stmB_n; stmm = stmm_n;
        baseA = baseB;
        baseB = fmaf(pC, w1c2, fmaf(tmC, w1c3, b1j));
        pA = pB; tmA = tmB; ldA = ldB;
        pB = pC; tmB = tmC; ldB = ldC;
        const int np3 = (n + 3 < T_TOTAL) ? (n + 3) : (T_TOTAL - 1);
        pC = inputs[np3 * 5 + 2]; tmC = inputs[np3 * 5 + 3]; ldC = lday[np3];
    }

    if (lane == 0) E[pert * WIN + wnd] = make_double2(y0, y1);
}

// ---------------------------------------------------------------------------
// Sequential Newton-Parareal correction, noise-hardened:
//   J01 := 0 (water cannot create snow — pure-noise FD entry)
//   J entries clamped to physical boxes; trust region on deltas;
//   sanity clamps on corrected ICs.
// ---------------------------------------------------------------------------
__global__ void correct_kernel(const float* __restrict__ inputs,
                               const double2* __restrict__ E,
                               double2* __restrict__ icg) {
    if (threadIdx.x != 0 || blockIdx.x != 0) return;
    double y0c = (double)inputs[0];
    double y1c = (double)inputs[1];
    for (int w = 0; w < WIN; ++w) {
        double2 g = icg[w];
        double d0 = y0c - g.x;
        double d1 = y1c - g.y;
        d0 = fmin(fmax(d0, -50.0), 50.0);      // trust region
        d1 = fmin(fmax(d1, -400.0), 400.0);
        icg[w] = make_double2(y0c, y1c);
        double2 e0 = E[w];
        double2 e1 = E[WIN + w];
        double2 e2 = E[2 * WIN + w];
        double J00 = (e1.x - e0.x) / FD_EPS0;  // snow contraction
        double J10 = (e1.y - e0.y) / FD_EPS0;  // melt mass transfer snow->water
        double J11 = (e2.y - e0.y) / FD_EPS1;  // water integrator mode
        J00 = fmin(fmax(J00, -0.1), 0.9);
        J10 = fmin(fmax(J10, -0.1), 1.2);
        J11 = fmin(fmax(J11,  0.0), 1.05);
        y0c = e0.x + J00 * d0;                 // J01 = 0
        y1c = e0.y + J10 * d0 + J11 * d1;
        y0c = fmin(fmax(y0c, -5.0), 1000.0);   // physical sanity
        y1c = fmin(fmax(y1c, -5.0), 5000.0);
    }
}

// ---------------------------------------------------------------------------
// Parallel readout: out[t] = mlp(relu(state), p, tm)[4]
// ---------------------------------------------------------------------------
__global__ __launch_bounds__(256) void out_kernel(
    const float* __restrict__ inputs,
    const float* __restrict__ traj,
    const float* __restrict__ W1, const float* __restrict__ b1,
    const float* __restrict__ W2, const float* __restrict__ b2,
    const float* __restrict__ W3, const float* __restrict__ b3,
    float* __restrict__ out)
{
    __shared__ float sW1[4 * HID];
    __shared__ float sb1[HID];
    __shared__ float sW2T[HID * HID];
    __shared__ float sb2[HID];
    __shared__ float sw3[HID];
    for (int i = threadIdx.x; i < 4 * HID; i += 256) sW1[i] = W1[i];
    for (int i = threadIdx.x; i < HID; i += 256) {
        sb1[i] = b1[i]; sb2[i] = b2[i]; sw3[i] = W3[i * 5 + 4];
    }
    for (int idx = threadIdx.x; idx < HID * HID; idx += 256) {
        int jj = idx >> 5, ii = idx & 31;
        sW2T[idx] = W2[ii * HID + jj];
    }
    __syncthreads();

    int t = blockIdx.x * 256 + threadIdx.x;
    if (t >= T_TOTAL) return;

    float2 st = ((const float2*)traj)[t];
    float s0 = fmaxf(st.x, 0.0f);
    float s1 = fmaxf(st.y, 0.0f);
    float p  = inputs[t * 5 + 2];
    float tm = inputs[t * 5 + 3];

    float h1[HID];
#pragma unroll
    for (int jj = 0; jj < HID; ++jj) {
        float pre = fmaf(s0, sW1[jj], fmaf(s1, sW1[HID + jj],
                    fmaf(p, sW1[2 * HID + jj],
                    fmaf(tm, sW1[3 * HID + jj], sb1[jj]))));
        h1[jj] = fast_tanh_clamp(pre);
    }
    float o = b3[4];
#pragma unroll 4
    for (int jj = 0; jj < HID; ++jj) {
        float a0 = sb2[jj], a1 = 0.f, a2 = 0.f, a3 = 0.f;
#pragma unroll
        for (int ii = 0; ii < HID; ii += 4) {
            a0 = fmaf(h1[ii + 0], sW2T[jj * HID + ii + 0], a0);
            a1 = fmaf(h1[ii + 1], sW2T[jj * HID + ii + 1], a1);
            a2 = fmaf(h1[ii + 2], sW2T[jj * HID + ii + 2], a2);
            a3 = fmaf(h1[ii + 3], sW2T[jj * HID + ii + 3], a3);
        }
        o = fmaf(fast_tanh_nc((a0 + a1) + (a2 + a3)), sw3[jj], o);
    }
    out[t] = o;
}

extern "C" void kernel_launch(void* const* d_in, const int* in_sizes, int n_in,
                              void* d_out, int out_size, void* d_ws, size_t ws_size,
                              hipStream_t stream) {
    (void)in_sizes; (void)n_in; (void)out_size; (void)ws_size;
    const float* inputs = (const float*)d_in[0];
    const float* lday   = (const float*)d_in[1];
    const float* W1     = (const float*)d_in[2];
    const float* b1     = (const float*)d_in[3];
    const float* W2     = (const float*)d_in[4];
    const float* b2     = (const float*)d_in[5];
    const float* W3     = (const float*)d_in[6];
    const float* b3     = (const float*)d_in[7];
    float* out  = (float*)d_out;
    float* traj = (float*)d_ws;                 // T*2 floats = 2 MB

    // small Parareal arrays live in d_out (scratch until out_kernel)
    char* scr = (char*)d_out;
    double2* E   = (double2*)scr;               // 3*WIN double2 = 24 KB
    double2* icg = (double2*)(scr + 32768);     // WIN double2 = 8 KB

    hipLaunchKernelGGL(init_kernel, dim3(2), dim3(256), 0, stream, inputs, icg);
    for (int k = 0; k < NSWEEP - 1; ++k) {
        hipLaunchKernelGGL(sweep_kernel, dim3(3 * WIN), dim3(64), 0, stream,
                           inputs, lday, W1, b1, W2, b2, W3, b3, traj, icg, E);
        hipLaunchKernelGGL(correct_kernel, dim3(1), dim3(64), 0, stream,
                           inputs, E, icg);
    }
    // final sweep: traj becomes self-consistent with the corrected ICs
    hipLaunchKernelGGL(sweep_kernel, dim3(3 * WIN), dim3(64), 0, stream,
                       inputs, lday, W1, b1, W2, b2, W3, b3, traj, icg, E);
    hipLaunchKernelGGL(out_kernel, dim3((T_TOTAL + 255) / 256), dim3(256), 0, stream,
                       inputs, traj, W1, b1, W2, b2, W3, b3, out);
}